// Round 1
// 313.335 us; speedup vs baseline: 1.0757x; 1.0757x over previous
//
#include <hip/hip_runtime.h>
#include <hip/hip_fp16.h>
#include <math.h>

#define S_LEN 2048
#define NHID  2048
#define D_HEAD 128
#define N_BH  32
#define EPS_Q 1e-8f

typedef _Float16 half8 __attribute__((ext_vector_type(8)));
typedef _Float16 half4 __attribute__((ext_vector_type(4)));
typedef float floatx4 __attribute__((ext_vector_type(4)));

// ---------------- kernel 1: per-(bh,chunk,d) partial sums of k and v ----------------
__global__ void means_kernel(const float* __restrict__ kk, const float* __restrict__ vv,
                             float* __restrict__ ksumP, float* __restrict__ vsumP) {
  int blk = blockIdx.x;            // 32 bh * 16 chunks of 128 rows
  int bh = blk >> 4, chunk = blk & 15;
  int b = bh >> 4, h = bh & 15;
  int t = threadIdx.x;
  int d4 = t & 31, sg = t >> 5;
  int s0 = chunk * 128;
  const long base = ((long)(b * S_LEN + s0)) * NHID + h * D_HEAD + d4 * 4;
  floatx4 ks = {0.f,0.f,0.f,0.f}, vs = {0.f,0.f,0.f,0.f};
  #pragma unroll 4
  for (int j = 0; j < 16; ++j) {
    long idx = base + (long)(sg * 16 + j) * NHID;
    ks += *(const floatx4*)(kk + idx);
    vs += *(const floatx4*)(vv + idx);
  }
  __shared__ floatx4 red[256];
  red[t] = ks; __syncthreads();
  if (t < 128) red[t] += red[t + 128]; __syncthreads();
  if (t < 64)  red[t] += red[t + 64];  __syncthreads();
  if (t < 32) *(floatx4*)(ksumP + (long)blk * 128 + t * 4) = red[t] + red[t + 32];
  __syncthreads();
  red[t] = vs; __syncthreads();
  if (t < 128) red[t] += red[t + 128]; __syncthreads();
  if (t < 64)  red[t] += red[t + 64];  __syncthreads();
  if (t < 32) *(floatx4*)(vsumP + (long)blk * 128 + t * 4) = red[t] + red[t + 32];
}

// ---------------- kernel 2 (fused): qquant | kquant | vprep ----------------
__global__ void prep_kernel(const float* __restrict__ q, const float* __restrict__ k,
                            const float* __restrict__ v,
                            const float* __restrict__ ksumP, const float* __restrict__ vsumP,
                            _Float16* __restrict__ qq, _Float16* __restrict__ kq,
                            _Float16* __restrict__ vt,
                            float* __restrict__ qscale, float* __restrict__ kscale,
                            float* __restrict__ vmean) {
  int blk = blockIdx.x;
  int t = threadIdx.x;
  int lane = t & 63, wid = t >> 6;
  __shared__ float wred[4];
  __shared__ __align__(16) _Float16 tile[64 * 136];
  int d4 = t & 31, sg = t >> 5;

  if (blk < 2048) {
    // ---- Q quant: 32 rows x 128 d
    int bh = blk >> 6, g = blk & 63;
    int b = bh >> 4, h = bh & 15;
    int s0 = g * 32;
    const long gbase = ((long)(b * S_LEN + s0)) * NHID + h * D_HEAD + d4 * 4;
    floatx4 vals[4]; float am = 0.f;
    #pragma unroll
    for (int j = 0; j < 4; ++j) {
      floatx4 x = *(const floatx4*)(q + gbase + (long)(sg + j * 8) * NHID);
      vals[j] = x;
      am = fmaxf(am, fmaxf(fmaxf(fabsf(x[0]), fabsf(x[1])), fmaxf(fabsf(x[2]), fabsf(x[3]))));
    }
    #pragma unroll
    for (int off = 1; off < 64; off <<= 1) am = fmaxf(am, __shfl_xor(am, off, 64));
    if (lane == 0) wred[wid] = am;
    __syncthreads();
    am = fmaxf(fmaxf(wred[0], wred[1]), fmaxf(wred[2], wred[3]));
    float scale = fmaxf(am / 127.0f, EPS_Q);
    if (t == 0) qscale[bh * 64 + g] = scale;
    float inv = 1.0f / scale;
    #pragma unroll
    for (int j = 0; j < 4; ++j) {
      half4 hv;
      #pragma unroll
      for (int c = 0; c < 4; ++c)
        hv[c] = (_Float16)fminf(fmaxf(rintf(vals[j][c] * inv), -127.f), 127.f);
      *(half4*)(qq + ((long)bh * S_LEN + s0 + sg + j * 8) * D_HEAD + d4 * 4) = hv;
    }
  } else if (blk < 3072) {
    // ---- K smooth+quant: 64 rows x 128 d
    int bb = blk - 2048;
    int bh = bb >> 5, g = bb & 31;
    int b = bh >> 4, h = bh & 15;
    int s0 = g * 64;
    floatx4 msum = {0.f,0.f,0.f,0.f};
    #pragma unroll
    for (int c = 0; c < 16; ++c)
      msum += *(const floatx4*)(ksumP + (long)(bh * 16 + c) * 128 + d4 * 4);
    floatx4 mean = msum * (1.0f / 2048.0f);
    const long gbase = ((long)(b * S_LEN + s0)) * NHID + h * D_HEAD + d4 * 4;
    floatx4 vals[8]; float am = 0.f;
    #pragma unroll
    for (int j = 0; j < 8; ++j) {
      floatx4 x = *(const floatx4*)(k + gbase + (long)(sg + j * 8) * NHID) - mean;
      vals[j] = x;
      am = fmaxf(am, fmaxf(fmaxf(fabsf(x[0]), fabsf(x[1])), fmaxf(fabsf(x[2]), fabsf(x[3]))));
    }
    #pragma unroll
    for (int off = 1; off < 64; off <<= 1) am = fmaxf(am, __shfl_xor(am, off, 64));
    if (lane == 0) wred[wid] = am;
    __syncthreads();
    am = fmaxf(fmaxf(wred[0], wred[1]), fmaxf(wred[2], wred[3]));
    float scale = fmaxf(am / 127.0f, EPS_Q);
    if (t == 0) kscale[bh * 32 + g] = scale;
    float inv = 1.0f / scale;
    #pragma unroll
    for (int j = 0; j < 8; ++j) {
      half4 hv;
      #pragma unroll
      for (int c = 0; c < 4; ++c)
        hv[c] = (_Float16)fminf(fmaxf(rintf(vals[j][c] * inv), -127.f), 127.f);
      *(half4*)(kq + ((long)bh * S_LEN + s0 + sg + j * 8) * D_HEAD + d4 * 4) = hv;
    }
  } else {
    // ---- V smooth -> fp16 transpose to [bh][d][s]
    int bb = blk - 3072;
    int bh = bb >> 5, st = bb & 31;
    int b = bh >> 4, h = bh & 15;
    int s0 = st * 64;
    floatx4 msum = {0.f,0.f,0.f,0.f};
    #pragma unroll
    for (int c = 0; c < 16; ++c)
      msum += *(const floatx4*)(vsumP + (long)(bh * 16 + c) * 128 + d4 * 4);
    floatx4 mean = msum * (1.0f / 2048.0f);
    if (st == 0 && sg == 0)
      *(floatx4*)(vmean + bh * D_HEAD + d4 * 4) = mean;
    const long gbase = ((long)(b * S_LEN + s0)) * NHID + h * D_HEAD + d4 * 4;
    #pragma unroll
    for (int j = 0; j < 8; ++j) {
      floatx4 x = *(const floatx4*)(v + gbase + (long)(sg + j * 8) * NHID) - mean;
      half4 hv = { (_Float16)x[0], (_Float16)x[1], (_Float16)x[2], (_Float16)x[3] };
      *(half4*)(tile + (sg + j * 8) * 136 + d4 * 4) = hv;
    }
    __syncthreads();
    int dr = t >> 1, sh = (t & 1) * 32;
    _Float16* dst = vt + ((long)bh * D_HEAD + dr) * S_LEN + s0 + sh;
    #pragma unroll
    for (int jo = 0; jo < 4; ++jo) {
      union { half8 v8; _Float16 h[8]; } u;
      #pragma unroll
      for (int ji = 0; ji < 8; ++ji) u.h[ji] = tile[(sh + jo * 8 + ji) * 136 + dr];
      *(half8*)(dst + jo * 8) = u.v8;
    }
  }
}

// ---------------- kernel 3: fused sliding-window attention ----------------
// v2: M_rep=2 — each wave owns 32 q-rows (block = 128 rows, grid 512). Every
// K/V fragment ds_read_b128 now feeds TWO MFMAs (halves LDS bytes per MFMA,
// which rocprof showed to be the bottleneck: MfmaUtil 11%, HBM 2%, heavy DS
// traffic). LDS: K(16K) + V(16K) + P(4 waves x 32x64 = 16K) = 48KB -> grid-
// limited 2 blocks/CU. launch_bounds(256,2): VGPR budget 256 (est ~220, the
// (256,3) budget of 170 would spill).
__launch_bounds__(256, 2)
__global__ void attn_kernel(const _Float16* __restrict__ qq, const _Float16* __restrict__ kq,
                            const _Float16* __restrict__ vt,
                            const float* __restrict__ qscale, const float* __restrict__ kscale,
                            const float* __restrict__ vmean,
                            const int* __restrict__ wlp, const int* __restrict__ wrp,
                            float* __restrict__ out) {
  int bid = blockIdx.x;
  // XCD swizzle (4 bh per XCD) + heavy/light pairing: bid and bid+256 share bh
  // and get qb, qb+8 whose window tile-counts sum ~constant (load balance).
  int xcd = bid & 7, rest = bid >> 3;
  int bh = xcd * 4 + (rest & 3);
  int qb = rest >> 2;
  int b = bh >> 4, h = bh & 15;
  int q0 = qb * 128;

  int wl = *wlp; if (wl < 0) wl = S_LEN;
  int wr = *wrp; if (wr < 0) wr = S_LEN;

  int t = threadIdx.x;
  int wv = t >> 6;
  int lane = t & 63;
  int ln = lane & 15;
  int qd = lane >> 4;
  int l7 = ln & 7;

  int r0 = q0 + wv * 32;                   // this wave's 32 q rows

  __shared__ __align__(16) _Float16 Kl[64 * 128];    // [key][d], chunk-XOR swizzled
  __shared__ __align__(16) _Float16 Vl[128 * 64];    // [d][key], chunk-XOR swizzled
  __shared__ __align__(16) _Float16 Pl[4][32 * 64];  // per-wave P (32 rows), swizzled

  // Q A-fragments resident for both 16-row halves: A[m=ln][k=qd*8+j]
  half8 qa[2][4];
  #pragma unroll
  for (int mh = 0; mh < 2; ++mh) {
    const _Float16* qbase = qq + ((long)bh * S_LEN + r0 + mh * 16 + ln) * D_HEAD + qd * 8;
    #pragma unroll
    for (int ks = 0; ks < 4; ++ks)
      qa[mh][ks] = *(const half8*)(qbase + ks * 32);
  }
  float qs = qscale[bh * 64 + (r0 >> 5)];  // r0 is 32-aligned: one scale for all 32 rows

  float mrow[2][4];
  floatx4 lacc[2];
  floatx4 oacc[2][8];
  #pragma unroll
  for (int mh = 0; mh < 2; ++mh) {
    #pragma unroll
    for (int r = 0; r < 4; ++r) { mrow[mh][r] = -1e30f; lacc[mh][r] = 0.f; }
    #pragma unroll
    for (int nd = 0; nd < 8; ++nd) oacc[mh][nd] = (floatx4){0.f,0.f,0.f,0.f};
  }

  // block-uniform tile range (all waves must iterate identically: barriers inside)
  int lo = q0 - wl; if (lo < 0) lo = 0;
  int hi = q0 + 127 + wr; if (hi > S_LEN - 1) hi = S_LEN - 1;
  int t_lo = lo >> 6, t_hi = hi >> 6;

  const float sm_scale = 0.08838834764831845f;  // 1/sqrt(128)
  const _Float16* kbase = kq + (long)bh * S_LEN * D_HEAD;
  const _Float16* vbase = vt + (long)bh * D_HEAD * S_LEN;
  const float* kscb = kscale + bh * 32;
  _Float16* pw = Pl[wv];
  const half8 vones = { (_Float16)1, (_Float16)1, (_Float16)1, (_Float16)1,
                        (_Float16)1, (_Float16)1, (_Float16)1, (_Float16)1 };

  // register prefetch of first tile (same gc decomposition as the stores below)
  half8 kpre[4], vpre[4];
  {
    int j0 = t_lo * 64;
    #pragma unroll
    for (int c = 0; c < 4; ++c) {
      int gc = t + c * 256;
      kpre[c] = *(const half8*)(kbase + (long)(j0 + (gc >> 4)) * D_HEAD + (gc & 15) * 8);
      vpre[c] = *(const half8*)(vbase + (long)(gc >> 3) * S_LEN + j0 + (gc & 7) * 8);
    }
  }

  for (int tt = t_lo; tt <= t_hi; ++tt) {
    int j0 = tt * 64;
    __syncthreads();                       // prev tile's LDS reads done
    #pragma unroll
    for (int c = 0; c < 4; ++c) {
      int gc = t + c * 256;
      {  // K: row 0..63, 16 chunks; swizzle low 3 bits of chunk by row
        int row = gc >> 4, ci = gc & 15;
        int cs = (ci & 8) | ((ci ^ row) & 7);
        *(half8*)(Kl + row * 128 + cs * 8) = kpre[c];
      }
      {  // V: d-row 0..127, 8 chunks
        int row = gc >> 3, ci = gc & 7;
        int cs = (ci ^ row) & 7;
        *(half8*)(Vl + row * 64 + cs * 8) = vpre[c];
      }
    }
    __syncthreads();
    if (tt < t_hi) {                       // issue next tile's global loads early
      int j1 = j0 + 64;
      #pragma unroll
      for (int c = 0; c < 4; ++c) {
        int gc = t + c * 256;
        kpre[c] = *(const half8*)(kbase + (long)(j1 + (gc >> 4)) * D_HEAD + (gc & 15) * 8);
        vpre[c] = *(const half8*)(vbase + (long)(gc >> 3) * S_LEN + j1 + (gc & 7) * 8);
      }
    }

    // wave-uniform skip: tile outside this wave's 32-row window
    if (j0 + 63 < r0 - wl || j0 > r0 + 31 + wr) continue;

    float dscale = qs * kscb[tt] * sm_scale;

    // S = Q K^T for both halves; each K frag read feeds 2 MFMAs
    floatx4 sacc[2][4];
    #pragma unroll
    for (int mh = 0; mh < 2; ++mh)
      #pragma unroll
      for (int nb = 0; nb < 4; ++nb) sacc[mh][nb] = (floatx4){0.f,0.f,0.f,0.f};
    #pragma unroll
    for (int nb = 0; nb < 4; ++nb)
      #pragma unroll
      for (int ks = 0; ks < 4; ++ks) {
        int ci = ks * 4 + qd;
        int cs = (ci & 8) | ((ci ^ ln) & 7);
        half8 kf = *(const half8*)(Kl + (nb * 16 + ln) * 128 + cs * 8);
        sacc[0][nb] = __builtin_amdgcn_mfma_f32_16x16x32_f16(qa[0][ks], kf, sacc[0][nb], 0, 0, 0);
        sacc[1][nb] = __builtin_amdgcn_mfma_f32_16x16x32_f16(qa[1][ks], kf, sacc[1][nb], 0, 0, 0);
      }

    // per-half: dequant + mask + online softmax, rescale, store P to LDS
    #pragma unroll
    for (int mh = 0; mh < 2; ++mh) {
      int rb = r0 + mh * 16;
      bool need_mask = (j0 < rb + 15 - wl) || (j0 + 63 > rb + wr);
      float p[4][4], alpha[4];
      #pragma unroll
      for (int r = 0; r < 4; ++r) {
        int row = rb + qd * 4 + r;
        float sv[4], mx = -1e30f;
        #pragma unroll
        for (int nb = 0; nb < 4; ++nb) {
          float s = sacc[mh][nb][r] * dscale;
          if (need_mask) {
            int col = j0 + nb * 16 + ln;
            bool ok = (row - col <= wl) && (col - row <= wr);
            s = ok ? s : -1e30f;
          }
          sv[nb] = s;
          mx = fmaxf(mx, s);
        }
        #pragma unroll
        for (int off = 1; off < 16; off <<= 1)
          mx = fmaxf(mx, __shfl_xor(mx, off, 64));
        float mnew = fmaxf(mrow[mh][r], mx);
        alpha[r] = __expf(mrow[mh][r] - mnew);
        mrow[mh][r] = mnew;
        #pragma unroll
        for (int nb = 0; nb < 4; ++nb)
          p[r][nb] = __expf(sv[nb] - mnew);
      }

      // rescale O and l for this half
      #pragma unroll
      for (int nd = 0; nd < 8; ++nd) {
        floatx4 o = oacc[mh][nd];
        #pragma unroll
        for (int r = 0; r < 4; ++r) o[r] *= alpha[r];
        oacc[mh][nd] = o;
      }
      #pragma unroll
      for (int r = 0; r < 4; ++r) lacc[mh][r] *= alpha[r];

      // P: C layout -> fp16 -> per-wave swizzled LDS (A-layout transpose)
      #pragma unroll
      for (int r = 0; r < 4; ++r) {
        int rw = qd * 4 + r;
        #pragma unroll
        for (int nb = 0; nb < 4; ++nb) {
          int ci = nb * 2 + (ln >> 3);
          int cs = (ci ^ rw) & 7;
          pw[(mh * 16 + rw) * 64 + cs * 8 + l7] = (_Float16)p[r][nb];
        }
      }
    }
    __threadfence_block();
    half8 pa[2][2];
    #pragma unroll
    for (int mh = 0; mh < 2; ++mh)
      #pragma unroll
      for (int ks = 0; ks < 2; ++ks) {
        int cs = ((ks * 4 + qd) ^ ln) & 7;
        pa[mh][ks] = *(const half8*)(pw + (mh * 16 + ln) * 64 + cs * 8);
      }

    // O += P Vhat; each V frag read feeds 2 MFMAs; l += P . 1 via ones-column MFMA
    #pragma unroll
    for (int nd = 0; nd < 8; ++nd)
      #pragma unroll
      for (int ks = 0; ks < 2; ++ks) {
        int cs = ((ks * 4 + qd) ^ ln) & 7;
        half8 vf = *(const half8*)(Vl + (nd * 16 + ln) * 64 + cs * 8);
        oacc[0][nd] = __builtin_amdgcn_mfma_f32_16x16x32_f16(pa[0][ks], vf, oacc[0][nd], 0, 0, 0);
        oacc[1][nd] = __builtin_amdgcn_mfma_f32_16x16x32_f16(pa[1][ks], vf, oacc[1][nd], 0, 0, 0);
      }
    #pragma unroll
    for (int mh = 0; mh < 2; ++mh) {
      lacc[mh] = __builtin_amdgcn_mfma_f32_16x16x32_f16(pa[mh][0], vones, lacc[mh], 0, 0, 0);
      lacc[mh] = __builtin_amdgcn_mfma_f32_16x16x32_f16(pa[mh][1], vones, lacc[mh], 0, 0, 0);
    }
  }

  // epilogue: out = fp16(O/l) + v_mean
  float vm[8];
  #pragma unroll
  for (int nd = 0; nd < 8; ++nd)
    vm[nd] = vmean[bh * D_HEAD + nd * 16 + ln];
  float* obase = out + ((long)b * S_LEN) * NHID + h * D_HEAD;
  #pragma unroll
  for (int mh = 0; mh < 2; ++mh)
    #pragma unroll
    for (int r = 0; r < 4; ++r) {
      int row = r0 + mh * 16 + qd * 4 + r;
      float linv = 1.0f / lacc[mh][r];
      #pragma unroll
      for (int nd = 0; nd < 8; ++nd) {
        float o16 = (float)(_Float16)(oacc[mh][nd][r] * linv);
        obase[(long)row * NHID + nd * 16 + ln] = o16 + vm[nd];
      }
    }
}

extern "C" void kernel_launch(void* const* d_in, const int* in_sizes, int n_in,
                              void* d_out, int out_size, void* d_ws, size_t ws_size,
                              hipStream_t stream) {
  (void)in_sizes; (void)n_in; (void)out_size; (void)ws_size;
  const float* q = (const float*)d_in[0];
  const float* k = (const float*)d_in[1];
  const float* v = (const float*)d_in[2];
  const int* wl = (const int*)d_in[3];
  const int* wr = (const int*)d_in[4];
  float* out = (float*)d_out;

  char* ws = (char*)d_ws;
  size_t off = 0;
  const size_t tensz = (size_t)N_BH * S_LEN * D_HEAD * sizeof(_Float16);  // 16.78 MB
  _Float16* qq = (_Float16*)(ws + off); off += tensz;
  _Float16* kq = (_Float16*)(ws + off); off += tensz;
  _Float16* vt = (_Float16*)(ws + off); off += tensz;
  float* ksumP  = (float*)(ws + off); off += (size_t)N_BH * 16 * 128 * sizeof(float);
  float* vsumP  = (float*)(ws + off); off += (size_t)N_BH * 16 * 128 * sizeof(float);
  float* vmean  = (float*)(ws + off); off += N_BH * D_HEAD * sizeof(float);
  float* qscale = (float*)(ws + off); off += N_BH * 64 * sizeof(float);
  float* kscale = (float*)(ws + off); off += N_BH * 32 * sizeof(float);

  means_kernel<<<512, 256, 0, stream>>>(k, v, ksumP, vsumP);
  prep_kernel<<<4096, 256, 0, stream>>>(q, k, v, ksumP, vsumP, qq, kq, vt, qscale, kscale, vmean);
  attn_kernel<<<512, 256, 0, stream>>>(qq, kq, vt, qscale, kscale, vmean, wl, wr, out);
}

// Round 2
// 246.353 us; speedup vs baseline: 1.3682x; 1.2719x over previous
//
#include <hip/hip_runtime.h>
#include <hip/hip_fp16.h>
#include <math.h>

#define S_LEN 2048
#define NHID  2048
#define D_HEAD 128
#define N_BH  32
#define EPS_Q 1e-8f

typedef _Float16 half8 __attribute__((ext_vector_type(8)));
typedef _Float16 half4 __attribute__((ext_vector_type(4)));
typedef float floatx4 __attribute__((ext_vector_type(4)));

// ---------------- kernel 1: per-(bh,chunk,d) partial sums of k and v ----------------
__global__ void means_kernel(const float* __restrict__ kk, const float* __restrict__ vv,
                             float* __restrict__ ksumP, float* __restrict__ vsumP) {
  int blk = blockIdx.x;            // 32 bh * 16 chunks of 128 rows
  int bh = blk >> 4, chunk = blk & 15;
  int b = bh >> 4, h = bh & 15;
  int t = threadIdx.x;
  int d4 = t & 31, sg = t >> 5;
  int s0 = chunk * 128;
  const long base = ((long)(b * S_LEN + s0)) * NHID + h * D_HEAD + d4 * 4;
  floatx4 ks = {0.f,0.f,0.f,0.f}, vs = {0.f,0.f,0.f,0.f};
  #pragma unroll 4
  for (int j = 0; j < 16; ++j) {
    long idx = base + (long)(sg * 16 + j) * NHID;
    ks += *(const floatx4*)(kk + idx);
    vs += *(const floatx4*)(vv + idx);
  }
  __shared__ floatx4 red[256];
  red[t] = ks; __syncthreads();
  if (t < 128) red[t] += red[t + 128]; __syncthreads();
  if (t < 64)  red[t] += red[t + 64];  __syncthreads();
  if (t < 32) *(floatx4*)(ksumP + (long)blk * 128 + t * 4) = red[t] + red[t + 32];
  __syncthreads();
  red[t] = vs; __syncthreads();
  if (t < 128) red[t] += red[t + 128]; __syncthreads();
  if (t < 64)  red[t] += red[t + 64];  __syncthreads();
  if (t < 32) *(floatx4*)(vsumP + (long)blk * 128 + t * 4) = red[t] + red[t + 32];
}

// ---------------- kernel 2 (fused): qquant | kquant | vprep ----------------
__global__ void prep_kernel(const float* __restrict__ q, const float* __restrict__ k,
                            const float* __restrict__ v,
                            const float* __restrict__ ksumP, const float* __restrict__ vsumP,
                            _Float16* __restrict__ qq, _Float16* __restrict__ kq,
                            _Float16* __restrict__ vt,
                            float* __restrict__ qscale, float* __restrict__ kscale,
                            float* __restrict__ vmean) {
  int blk = blockIdx.x;
  int t = threadIdx.x;
  int lane = t & 63, wid = t >> 6;
  __shared__ float wred[4];
  __shared__ __align__(16) _Float16 tile[64 * 136];
  int d4 = t & 31, sg = t >> 5;

  if (blk < 2048) {
    // ---- Q quant: 32 rows x 128 d
    int bh = blk >> 6, g = blk & 63;
    int b = bh >> 4, h = bh & 15;
    int s0 = g * 32;
    const long gbase = ((long)(b * S_LEN + s0)) * NHID + h * D_HEAD + d4 * 4;
    floatx4 vals[4]; float am = 0.f;
    #pragma unroll
    for (int j = 0; j < 4; ++j) {
      floatx4 x = *(const floatx4*)(q + gbase + (long)(sg + j * 8) * NHID);
      vals[j] = x;
      am = fmaxf(am, fmaxf(fmaxf(fabsf(x[0]), fabsf(x[1])), fmaxf(fabsf(x[2]), fabsf(x[3]))));
    }
    #pragma unroll
    for (int off = 1; off < 64; off <<= 1) am = fmaxf(am, __shfl_xor(am, off, 64));
    if (lane == 0) wred[wid] = am;
    __syncthreads();
    am = fmaxf(fmaxf(wred[0], wred[1]), fmaxf(wred[2], wred[3]));
    float scale = fmaxf(am / 127.0f, EPS_Q);
    if (t == 0) qscale[bh * 64 + g] = scale;
    float inv = 1.0f / scale;
    #pragma unroll
    for (int j = 0; j < 4; ++j) {
      half4 hv;
      #pragma unroll
      for (int c = 0; c < 4; ++c)
        hv[c] = (_Float16)fminf(fmaxf(rintf(vals[j][c] * inv), -127.f), 127.f);
      *(half4*)(qq + ((long)bh * S_LEN + s0 + sg + j * 8) * D_HEAD + d4 * 4) = hv;
    }
  } else if (blk < 3072) {
    // ---- K smooth+quant: 64 rows x 128 d
    int bb = blk - 2048;
    int bh = bb >> 5, g = bb & 31;
    int b = bh >> 4, h = bh & 15;
    int s0 = g * 64;
    floatx4 msum = {0.f,0.f,0.f,0.f};
    #pragma unroll
    for (int c = 0; c < 16; ++c)
      msum += *(const floatx4*)(ksumP + (long)(bh * 16 + c) * 128 + d4 * 4);
    floatx4 mean = msum * (1.0f / 2048.0f);
    const long gbase = ((long)(b * S_LEN + s0)) * NHID + h * D_HEAD + d4 * 4;
    floatx4 vals[8]; float am = 0.f;
    #pragma unroll
    for (int j = 0; j < 8; ++j) {
      floatx4 x = *(const floatx4*)(k + gbase + (long)(sg + j * 8) * NHID) - mean;
      vals[j] = x;
      am = fmaxf(am, fmaxf(fmaxf(fabsf(x[0]), fabsf(x[1])), fmaxf(fabsf(x[2]), fabsf(x[3]))));
    }
    #pragma unroll
    for (int off = 1; off < 64; off <<= 1) am = fmaxf(am, __shfl_xor(am, off, 64));
    if (lane == 0) wred[wid] = am;
    __syncthreads();
    am = fmaxf(fmaxf(wred[0], wred[1]), fmaxf(wred[2], wred[3]));
    float scale = fmaxf(am / 127.0f, EPS_Q);
    if (t == 0) kscale[bh * 32 + g] = scale;
    float inv = 1.0f / scale;
    #pragma unroll
    for (int j = 0; j < 8; ++j) {
      half4 hv;
      #pragma unroll
      for (int c = 0; c < 4; ++c)
        hv[c] = (_Float16)fminf(fmaxf(rintf(vals[j][c] * inv), -127.f), 127.f);
      *(half4*)(kq + ((long)bh * S_LEN + s0 + sg + j * 8) * D_HEAD + d4 * 4) = hv;
    }
  } else {
    // ---- V smooth -> fp16 transpose to [bh][d][s]
    int bb = blk - 3072;
    int bh = bb >> 5, st = bb & 31;
    int b = bh >> 4, h = bh & 15;
    int s0 = st * 64;
    floatx4 msum = {0.f,0.f,0.f,0.f};
    #pragma unroll
    for (int c = 0; c < 16; ++c)
      msum += *(const floatx4*)(vsumP + (long)(bh * 16 + c) * 128 + d4 * 4);
    floatx4 mean = msum * (1.0f / 2048.0f);
    if (st == 0 && sg == 0)
      *(floatx4*)(vmean + bh * D_HEAD + d4 * 4) = mean;
    const long gbase = ((long)(b * S_LEN + s0)) * NHID + h * D_HEAD + d4 * 4;
    #pragma unroll
    for (int j = 0; j < 8; ++j) {
      floatx4 x = *(const floatx4*)(v + gbase + (long)(sg + j * 8) * NHID) - mean;
      half4 hv = { (_Float16)x[0], (_Float16)x[1], (_Float16)x[2], (_Float16)x[3] };
      *(half4*)(tile + (sg + j * 8) * 136 + d4 * 4) = hv;
    }
    __syncthreads();
    int dr = t >> 1, sh = (t & 1) * 32;
    _Float16* dst = vt + ((long)bh * D_HEAD + dr) * S_LEN + s0 + sh;
    #pragma unroll
    for (int jo = 0; jo < 4; ++jo) {
      union { half8 v8; _Float16 h[8]; } u;
      #pragma unroll
      for (int ji = 0; ji < 8; ++ji) u.h[ji] = tile[(sh + jo * 8 + ji) * 136 + dr];
      *(half8*)(dst + jo * 8) = u.v8;
    }
  }
}

// ---------------- kernel 3: fused sliding-window attention ----------------
// v3: swapped-operand QK^T (mfma(K,Q) -> S^T layout). Each lane holds a full
// 16-value slice of ONE q-row per half -> softmax max is in-lane tree + 2
// shuffles; P is packed in-register into the PV A-fragment (key-permutation
// applied consistently to V B-frag reads) -> the entire P LDS round-trip
// (64 ds_write_b16 + fence + 4 ds_read_b128 per wave-tile) is GONE.
// Defer-max (THR=8): skip O/l rescale when no row max grows. LDS 32KB.
__launch_bounds__(256, 2)
__global__ void attn_kernel(const _Float16* __restrict__ qq, const _Float16* __restrict__ kq,
                            const _Float16* __restrict__ vt,
                            const float* __restrict__ qscale, const float* __restrict__ kscale,
                            const float* __restrict__ vmean,
                            const int* __restrict__ wlp, const int* __restrict__ wrp,
                            float* __restrict__ out) {
  int bid = blockIdx.x;
  int xcd = bid & 7, rest = bid >> 3;
  int bh = xcd * 4 + (rest & 3);
  int qb = rest >> 2;
  int b = bh >> 4, h = bh & 15;
  int q0 = qb * 128;

  int wl = *wlp; if (wl < 0) wl = S_LEN;
  int wr = *wrp; if (wr < 0) wr = S_LEN;

  int t = threadIdx.x;
  int wv = t >> 6;
  int lane = t & 63;
  int ln = lane & 15;
  int qd = lane >> 4;

  int r0 = q0 + wv * 32;                   // this wave's 32 q rows

  __shared__ __align__(16) _Float16 Kl[64 * 128];    // [key][d], chunk-XOR swizzled
  __shared__ __align__(16) _Float16 Vl[128 * 64];    // [d][key], chunk-XOR swizzled

  // Q fragments (used as MFMA B operand): lane (qd,ln) holds Q[r0+mh*16+ln][qd*8+j+32ks]
  half8 qa[2][4];
  #pragma unroll
  for (int mh = 0; mh < 2; ++mh) {
    const _Float16* qbase = qq + ((long)bh * S_LEN + r0 + mh * 16 + ln) * D_HEAD + qd * 8;
    #pragma unroll
    for (int ks = 0; ks < 4; ++ks)
      qa[mh][ks] = *(const half8*)(qbase + ks * 32);
  }
  float qs = qscale[bh * 64 + (r0 >> 5)];

  float mrow[2];                            // running max for q-row (ln) per half
  floatx4 lacc[2];                          // l in C-layout rows qd*4+r (matches oacc)
  floatx4 oacc[2][8];
  #pragma unroll
  for (int mh = 0; mh < 2; ++mh) {
    mrow[mh] = -1e30f;
    #pragma unroll
    for (int r = 0; r < 4; ++r) lacc[mh][r] = 0.f;
    #pragma unroll
    for (int nd = 0; nd < 8; ++nd) oacc[mh][nd] = (floatx4){0.f,0.f,0.f,0.f};
  }

  int lo = q0 - wl; if (lo < 0) lo = 0;
  int hi = q0 + 127 + wr; if (hi > S_LEN - 1) hi = S_LEN - 1;
  int t_lo = lo >> 6, t_hi = hi >> 6;

  const float sm_scale = 0.08838834764831845f;  // 1/sqrt(128)
  const _Float16* kbase = kq + (long)bh * S_LEN * D_HEAD;
  const _Float16* vbase = vt + (long)bh * D_HEAD * S_LEN;
  const float* kscb = kscale + bh * 32;
  const half8 vones = { (_Float16)1, (_Float16)1, (_Float16)1, (_Float16)1,
                        (_Float16)1, (_Float16)1, (_Float16)1, (_Float16)1 };

  // register prefetch of first tile (same gc decomposition as the stores below)
  half8 kpre[4], vpre[4];
  {
    int j0 = t_lo * 64;
    #pragma unroll
    for (int c = 0; c < 4; ++c) {
      int gc = t + c * 256;
      kpre[c] = *(const half8*)(kbase + (long)(j0 + (gc >> 4)) * D_HEAD + (gc & 15) * 8);
      vpre[c] = *(const half8*)(vbase + (long)(gc >> 3) * S_LEN + j0 + (gc & 7) * 8);
    }
  }

  for (int tt = t_lo; tt <= t_hi; ++tt) {
    int j0 = tt * 64;
    __syncthreads();                       // prev tile's LDS reads done
    #pragma unroll
    for (int c = 0; c < 4; ++c) {
      int gc = t + c * 256;
      {  // K: row 0..63, 16 chunks; swizzle low 3 bits of chunk by row
        int row = gc >> 4, ci = gc & 15;
        int cs = (ci & 8) | ((ci ^ row) & 7);
        *(half8*)(Kl + row * 128 + cs * 8) = kpre[c];
      }
      {  // V: d-row 0..127, 8 chunks
        int row = gc >> 3, ci = gc & 7;
        int cs = (ci ^ row) & 7;
        *(half8*)(Vl + row * 64 + cs * 8) = vpre[c];
      }
    }
    __syncthreads();
    if (tt < t_hi) {                       // issue next tile's global loads early
      int j1 = j0 + 64;
      #pragma unroll
      for (int c = 0; c < 4; ++c) {
        int gc = t + c * 256;
        kpre[c] = *(const half8*)(kbase + (long)(j1 + (gc >> 4)) * D_HEAD + (gc & 15) * 8);
        vpre[c] = *(const half8*)(vbase + (long)(gc >> 3) * S_LEN + j1 + (gc & 7) * 8);
      }
    }

    // wave-uniform skip: tile outside this wave's 32-row window
    if (j0 + 63 < r0 - wl || j0 > r0 + 31 + wr) continue;

    float dscale = qs * kscb[tt] * sm_scale;

    // S^T = K Q^T : mfma(A=K-frag, B=Q-frag). Lane (qd,ln) gets, per nb,
    // S[qrow=ln][key = nb*16 + qd*4 + r] in sacc[mh][nb][r].
    floatx4 sacc[2][4];
    #pragma unroll
    for (int mh = 0; mh < 2; ++mh)
      #pragma unroll
      for (int nb = 0; nb < 4; ++nb) sacc[mh][nb] = (floatx4){0.f,0.f,0.f,0.f};
    #pragma unroll
    for (int nb = 0; nb < 4; ++nb)
      #pragma unroll
      for (int ks = 0; ks < 4; ++ks) {
        int ci = ks * 4 + qd;
        int cs = (ci & 8) | ((ci ^ ln) & 7);
        half8 kf = *(const half8*)(Kl + (nb * 16 + ln) * 128 + cs * 8);
        sacc[0][nb] = __builtin_amdgcn_mfma_f32_16x16x32_f16(kf, qa[0][ks], sacc[0][nb], 0, 0, 0);
        sacc[1][nb] = __builtin_amdgcn_mfma_f32_16x16x32_f16(kf, qa[1][ks], sacc[1][nb], 0, 0, 0);
      }

    // per-half: dequant + mask + online softmax (row = ln, fully in-lane +
    // 2 shuffles), defer-max rescale, in-register P pack into PV A-frags.
    half8 pa[2][2];
    #pragma unroll
    for (int mh = 0; mh < 2; ++mh) {
      int rb = r0 + mh * 16;
      bool need_mask = (j0 < rb + 15 - wl) || (j0 + 63 > rb + wr);
      int row = rb + ln;
      float sv[4][4];                      // [nb][r]
      float mnb[4];
      #pragma unroll
      for (int nb = 0; nb < 4; ++nb) {
        #pragma unroll
        for (int r = 0; r < 4; ++r) {
          float s = sacc[mh][nb][r] * dscale;
          if (need_mask) {
            int col = j0 + nb * 16 + qd * 4 + r;
            bool ok = (row - col <= wl) && (col - row <= wr);
            s = ok ? s : -1e30f;
          }
          sv[nb][r] = s;
        }
        mnb[nb] = fmaxf(fmaxf(sv[nb][0], sv[nb][1]), fmaxf(sv[nb][2], sv[nb][3]));
      }
      float mx = fmaxf(fmaxf(mnb[0], mnb[1]), fmaxf(mnb[2], mnb[3]));
      mx = fmaxf(mx, __shfl_xor(mx, 16, 64));
      mx = fmaxf(mx, __shfl_xor(mx, 32, 64));

      if (__any(mx > mrow[mh] + 8.0f)) {   // defer-max: rescale only on growth
        float mnew = fmaxf(mrow[mh], mx);
        float alpha = __expf(mrow[mh] - mnew);
        mrow[mh] = mnew;
        float ar[4];                       // alpha for C-layout rows qd*4+r
        #pragma unroll
        for (int r = 0; r < 4; ++r) ar[r] = __shfl(alpha, qd * 4 + r, 64);
        #pragma unroll
        for (int nd = 0; nd < 8; ++nd) {
          floatx4 o = oacc[mh][nd];
          #pragma unroll
          for (int r = 0; r < 4; ++r) o[r] *= ar[r];
          oacc[mh][nd] = o;
        }
        #pragma unroll
        for (int r = 0; r < 4; ++r) lacc[mh][r] *= ar[r];
      }

      float m0 = mrow[mh];
      // A-frag slot (ks, lane qd, j): j=0..3 -> key 32ks+qd*4+j ; j=4..7 -> key 32ks+16+qd*4+(j-4)
      #pragma unroll
      for (int ks = 0; ks < 2; ++ks) {
        half8 tf;
        #pragma unroll
        for (int r = 0; r < 4; ++r) {
          tf[r]     = (_Float16)__expf(sv[2 * ks][r] - m0);
          tf[4 + r] = (_Float16)__expf(sv[2 * ks + 1][r] - m0);
        }
        pa[mh][ks] = tf;
      }
    }

    // O += P Vhat. V B-frag uses the SAME key permutation: slot (ks,qd,j) ->
    // key 32ks + 16*(j>>2) + qd*4 + (j&3): two b64 chunks at +0 and +16 keys.
    #pragma unroll
    for (int nd = 0; nd < 8; ++nd) {
      int rowv = nd * 16 + ln;
      #pragma unroll
      for (int ks = 0; ks < 2; ++ks) {
        int ci0 = ks * 4 + (qd >> 1);
        int o4 = (qd & 1) * 4;
        int cs0 = (ci0 ^ rowv) & 7;
        int cs1 = ((ci0 + 2) ^ rowv) & 7;
        half4 v0 = *(const half4*)(Vl + rowv * 64 + cs0 * 8 + o4);
        half4 v1 = *(const half4*)(Vl + rowv * 64 + cs1 * 8 + o4);
        half8 vf = { v0[0], v0[1], v0[2], v0[3], v1[0], v1[1], v1[2], v1[3] };
        oacc[0][nd] = __builtin_amdgcn_mfma_f32_16x16x32_f16(pa[0][ks], vf, oacc[0][nd], 0, 0, 0);
        oacc[1][nd] = __builtin_amdgcn_mfma_f32_16x16x32_f16(pa[1][ks], vf, oacc[1][nd], 0, 0, 0);
      }
    }
    #pragma unroll
    for (int mh = 0; mh < 2; ++mh) {
      lacc[mh] = __builtin_amdgcn_mfma_f32_16x16x32_f16(pa[mh][0], vones, lacc[mh], 0, 0, 0);
      lacc[mh] = __builtin_amdgcn_mfma_f32_16x16x32_f16(pa[mh][1], vones, lacc[mh], 0, 0, 0);
    }
  }

  // epilogue: out = fp16(O/l) + v_mean  (oacc/lacc rows = qd*4+r, cols = ln)
  float vm[8];
  #pragma unroll
  for (int nd = 0; nd < 8; ++nd)
    vm[nd] = vmean[bh * D_HEAD + nd * 16 + ln];
  float* obase = out + ((long)b * S_LEN) * NHID + h * D_HEAD;
  #pragma unroll
  for (int mh = 0; mh < 2; ++mh)
    #pragma unroll
    for (int r = 0; r < 4; ++r) {
      int row = r0 + mh * 16 + qd * 4 + r;
      float linv = 1.0f / lacc[mh][r];
      #pragma unroll
      for (int nd = 0; nd < 8; ++nd) {
        float o16 = (float)(_Float16)(oacc[mh][nd][r] * linv);
        obase[(long)row * NHID + nd * 16 + ln] = o16 + vm[nd];
      }
    }
}

extern "C" void kernel_launch(void* const* d_in, const int* in_sizes, int n_in,
                              void* d_out, int out_size, void* d_ws, size_t ws_size,
                              hipStream_t stream) {
  (void)in_sizes; (void)n_in; (void)out_size; (void)ws_size;
  const float* q = (const float*)d_in[0];
  const float* k = (const float*)d_in[1];
  const float* v = (const float*)d_in[2];
  const int* wl = (const int*)d_in[3];
  const int* wr = (const int*)d_in[4];
  float* out = (float*)d_out;

  char* ws = (char*)d_ws;
  size_t off = 0;
  const size_t tensz = (size_t)N_BH * S_LEN * D_HEAD * sizeof(_Float16);  // 16.78 MB
  _Float16* qq = (_Float16*)(ws + off); off += tensz;
  _Float16* kq = (_Float16*)(ws + off); off += tensz;
  _Float16* vt = (_Float16*)(ws + off); off += tensz;
  float* ksumP  = (float*)(ws + off); off += (size_t)N_BH * 16 * 128 * sizeof(float);
  float* vsumP  = (float*)(ws + off); off += (size_t)N_BH * 16 * 128 * sizeof(float);
  float* vmean  = (float*)(ws + off); off += N_BH * D_HEAD * sizeof(float);
  float* qscale = (float*)(ws + off); off += N_BH * 64 * sizeof(float);
  float* kscale = (float*)(ws + off); off += N_BH * 32 * sizeof(float);

  means_kernel<<<512, 256, 0, stream>>>(k, v, ksumP, vsumP);
  prep_kernel<<<4096, 256, 0, stream>>>(q, k, v, ksumP, vsumP, qq, kq, vt, qscale, kscale, vmean);
  attn_kernel<<<512, 256, 0, stream>>>(qq, kq, vt, qscale, kscale, vmean, wl, wr, out);
}